// Round 1
// baseline (6168.297 us; speedup 1.0000x reference)
//
#include <hip/hip_runtime.h>

#define DD 128
#define NREL 8
#define BM 64
#define LDH 132   // LDS row stride (words): 132%32=4 -> 2-way max conflict; 528B rows keep float4 alignment

__device__ __forceinline__ float dis_f(float deg) {
    return deg == 0.0f ? 1.0f : rsqrtf(deg);
}

// Pass 1: in-degree (over col) + histogram of edge types
__global__ void deg_hist_kernel(const int* __restrict__ ei, const int* __restrict__ et,
                                float* __restrict__ deg, int* __restrict__ cnt, int E) {
    int e = blockIdx.x * blockDim.x + threadIdx.x;
    if (e >= E) return;
    atomicAdd(&deg[ei[E + e]], 1.0f);
    atomicAdd(&cnt[et[e]], 1);
}

// Tiny prefix sum over 8 relation counts
__global__ void offs_kernel(const int* __restrict__ cnt, int* __restrict__ offs,
                            int* __restrict__ cursor) {
    int s = 0;
    for (int r = 0; r < NREL; ++r) { offs[r] = s; cursor[r] = s; s += cnt[r]; }
    offs[NREL] = s;
}

// Counting-sort edges by relation; record = (row<<16|col, coef). Requires N < 65536.
__global__ void bucket_kernel(const int* __restrict__ ei, const int* __restrict__ et,
                              const float* __restrict__ ew, const float* __restrict__ deg,
                              int* __restrict__ cursor, uint2* __restrict__ ebuf, int E) {
    int e = blockIdx.x * blockDim.x + threadIdx.x;
    if (e >= E) return;
    int row = ei[e], col = ei[E + e];
    float coef = dis_f(deg[row]) * dis_f(deg[col]) * ew[e];
    int pos = atomicAdd(&cursor[et[e]], 1);
    ebuf[pos] = make_uint2(((unsigned)row << 16) | (unsigned)col, __float_as_uint(coef));
}

// Scatter one relation bucket: h[col,:] += coef * src[row,:]
// 128 lanes per edge (d = lane), 2 edges per 256-thread block per step, grid-stride.
__global__ __launch_bounds__(256) void scatter_kernel(const uint2* __restrict__ ebuf,
                                                      const int* __restrict__ offs, int r,
                                                      const float* __restrict__ src,
                                                      float* __restrict__ hbuf) {
    const int beg = offs[r], end = offs[r + 1];
    const int d = threadIdx.x & (DD - 1);
    const int half = threadIdx.x >> 7;
    const int step = gridDim.x * 2;
    for (int e = beg + blockIdx.x * 2 + half; e < end; e += step) {
        const uint2 rec = ebuf[e];
        const int row = rec.x >> 16, col = rec.x & 0xFFFF;
        const float coef = __uint_as_float(rec.y);
        atomicAdd(&hbuf[(size_t)col * DD + d], coef * src[(size_t)row * DD + d]);
    }
}

// zacc[n,0:128] += h[n,0:128] @ W[128,128]; zeroes consumed h tile behind itself.
// Block: 256 thr = 16x16; thread (i,j) owns rows i*4..i*4+3, cols j*8..j*8+7.
__global__ __launch_bounds__(256) void gemm_kernel(float* __restrict__ hbuf,
                                                   const float* __restrict__ W,
                                                   float* __restrict__ zacc, int N) {
    __shared__ float lds[BM * LDH];
    const int t = threadIdx.x;
    const int m0 = blockIdx.x * BM;

    // Stage h tile to LDS; zero global h behind us (ready for next relation's atomics).
    #pragma unroll
    for (int v = t; v < BM * 32; v += 256) {
        const int row = v >> 5, c4 = v & 31;
        const int gr = m0 + row;
        float4 val = make_float4(0.f, 0.f, 0.f, 0.f);
        if (gr < N) {
            float4* gp = (float4*)&hbuf[(size_t)gr * DD + c4 * 4];
            val = *gp;
            *gp = make_float4(0.f, 0.f, 0.f, 0.f);
        }
        *(float4*)&lds[row * LDH + c4 * 4] = val;
    }
    __syncthreads();

    const int i = t >> 4, j = t & 15;
    float acc[4][8];
    #pragma unroll
    for (int m = 0; m < 4; ++m)
        #pragma unroll
        for (int c = 0; c < 8; ++c) acc[m][c] = 0.f;

    const float* lh = &lds[(i * 4) * LDH];
    const float* Wp = W + j * 8;
    #pragma unroll 4
    for (int k = 0; k < DD; ++k) {
        const float4 wa = *(const float4*)&Wp[(size_t)k * DD];
        const float4 wb = *(const float4*)&Wp[(size_t)k * DD + 4];
        float a[4];
        #pragma unroll
        for (int m = 0; m < 4; ++m) a[m] = lh[m * LDH + k];
        #pragma unroll
        for (int m = 0; m < 4; ++m) {
            acc[m][0] += a[m] * wa.x; acc[m][1] += a[m] * wa.y;
            acc[m][2] += a[m] * wa.z; acc[m][3] += a[m] * wa.w;
            acc[m][4] += a[m] * wb.x; acc[m][5] += a[m] * wb.y;
            acc[m][6] += a[m] * wb.z; acc[m][7] += a[m] * wb.w;
        }
    }

    #pragma unroll
    for (int m = 0; m < 4; ++m) {
        const int gr = m0 + i * 4 + m;
        if (gr >= N) continue;
        float4* p = (float4*)&zacc[(size_t)gr * DD + j * 8];
        float4 v0 = p[0], v1 = p[1];
        v0.x += acc[m][0]; v0.y += acc[m][1]; v0.z += acc[m][2]; v0.w += acc[m][3];
        v1.x += acc[m][4]; v1.y += acc[m][5]; v1.z += acc[m][6]; v1.w += acc[m][7];
        p[0] = v0; p[1] = v1;
    }
}

// z = leaky_relu(z + b, 0.01) in place (float4 over N*D)
__global__ void act_kernel(float* __restrict__ z, const float* __restrict__ b, int total4) {
    int idx = blockIdx.x * blockDim.x + threadIdx.x;
    if (idx >= total4) return;
    const int c0 = (idx * 4) & (DD - 1);
    float4 v = ((float4*)z)[idx];
    v.x += b[c0 + 0]; v.y += b[c0 + 1]; v.z += b[c0 + 2]; v.w += b[c0 + 3];
    v.x = v.x >= 0.f ? v.x : 0.01f * v.x;
    v.y = v.y >= 0.f ? v.y : 0.01f * v.y;
    v.z = v.z >= 0.f ? v.z : 0.01f * v.z;
    v.w = v.w >= 0.f ? v.w : 0.01f * v.w;
    ((float4*)z)[idx] = v;
}

// out[0:T) holds z1, out[T:2T) holds conv2 pre-bias; rewrite to (z_star, z_sharp).
__global__ void final_kernel(const float* __restrict__ x, const float* __restrict__ b2,
                             float* __restrict__ out, int total4) {
    int idx = blockIdx.x * blockDim.x + threadIdx.x;
    if (idx >= total4) return;
    const int c0 = (idx * 4) & (DD - 1);
    float4 z1 = ((float4*)out)[idx];
    float4 z2 = ((float4*)out)[total4 + idx];
    z2.x += b2[c0 + 0]; z2.y += b2[c0 + 1]; z2.z += b2[c0 + 2]; z2.w += b2[c0 + 3];
    float4 xx = ((const float4*)x)[idx];
    float4 zs, zp;
    zs.x = (xx.x + z1.x + z2.x) * 0.25f; zp.x = (z1.x + z2.x) * (1.f / 3.f);
    zs.y = (xx.y + z1.y + z2.y) * 0.25f; zp.y = (z1.y + z2.y) * (1.f / 3.f);
    zs.z = (xx.z + z1.z + z2.z) * 0.25f; zp.z = (z1.z + z2.z) * (1.f / 3.f);
    zs.w = (xx.w + z1.w + z2.w) * 0.25f; zp.w = (z1.w + z2.w) * (1.f / 3.f);
    ((float4*)out)[idx] = zs;
    ((float4*)out)[total4 + idx] = zp;
}

extern "C" void kernel_launch(void* const* d_in, const int* in_sizes, int n_in,
                              void* d_out, int out_size, void* d_ws, size_t ws_size,
                              hipStream_t stream) {
    const float* x  = (const float*)d_in[0];
    const int*   ei = (const int*)d_in[1];
    const int*   et = (const int*)d_in[2];
    const float* ew = (const float*)d_in[3];
    const float* W1 = (const float*)d_in[4];
    const float* b1 = (const float*)d_in[5];
    const float* W2 = (const float*)d_in[6];
    const float* b2 = (const float*)d_in[7];

    const int N = in_sizes[0] / DD;
    const int E = in_sizes[3];
    const int total = N * DD;
    float* out = (float*)d_out;

    // ws layout: deg[Npad] | cnt[16],offs[16],cursor[16] | ebuf[E]*8B | hbuf[N*D]
    char* w = (char*)d_ws;
    const size_t npad = (size_t)((N + 15) / 16) * 16;
    float* deg = (float*)w;            w += npad * 4;
    int* cnt = (int*)w;                w += 64 * 4;
    int* offs = cnt + 16;
    int* cursor = cnt + 32;
    uint2* ebuf = (uint2*)w;           w += (size_t)E * 8;
    float* hbuf = (float*)w;

    // Per-call init (harness poisons out/ws once; we RMW-accumulate into out halves).
    hipMemsetAsync(d_ws, 0, npad * 4 + 256, stream);                  // deg + cnt/offs/cursor
    hipMemsetAsync(hbuf, 0, (size_t)total * 4, stream);               // atomic target
    hipMemsetAsync(d_out, 0, (size_t)total * 2 * 4, stream);          // z1acc | z2acc

    const int eb = (E + 255) / 256;
    deg_hist_kernel<<<eb, 256, 0, stream>>>(ei, et, deg, cnt, E);
    offs_kernel<<<1, 1, 0, stream>>>(cnt, offs, cursor);
    bucket_kernel<<<eb, 256, 0, stream>>>(ei, et, ew, deg, cursor, ebuf, E);

    const int nb = (N + BM - 1) / BM;
    float* z1acc = out;
    float* z2acc = out + total;

    for (int r = 0; r < NREL; ++r) {
        scatter_kernel<<<1024, 256, 0, stream>>>(ebuf, offs, r, x, hbuf);
        gemm_kernel<<<nb, 256, 0, stream>>>(hbuf, W1 + (size_t)r * DD * DD, z1acc, N);
    }
    const int t4 = total / 4;
    act_kernel<<<(t4 + 255) / 256, 256, 0, stream>>>(z1acc, b1, t4);

    for (int r = 0; r < NREL; ++r) {
        scatter_kernel<<<1024, 256, 0, stream>>>(ebuf, offs, r, z1acc, hbuf);
        gemm_kernel<<<nb, 256, 0, stream>>>(hbuf, W2 + (size_t)r * DD * DD, z2acc, N);
    }
    final_kernel<<<(t4 + 255) / 256, 256, 0, stream>>>(x, b2, out, t4);
}

// Round 2
// 1383.056 us; speedup vs baseline: 4.4599x; 4.4599x over previous
//
#include <hip/hip_runtime.h>

#define DD 128
#define NREL 8
#define BM 64
#define LDH 132   // LDS row stride (words): 132%32=4 -> 2-way max conflict; float4-aligned rows
#define NBLK 256  // blocks for count/bucket passes; NBLK*NREL must equal 2048 (= 256 thr * 8)

__device__ __forceinline__ float dis_f(float deg) {
    return deg == 0.0f ? 1.0f : rsqrtf(deg);
}

// Pass A: in-degree atomics (50K addresses, benign) + per-block relation histogram in LDS.
// No global atomics to small-radix arrays (that was 2.4ms of serialized L2 RMW in round 1).
__global__ __launch_bounds__(256) void count_deg_kernel(const int* __restrict__ ei,
                                                        const int* __restrict__ et,
                                                        float* __restrict__ deg,
                                                        int* __restrict__ blkcnt,
                                                        int E, int chunk) {
    __shared__ int h[NREL];
    if (threadIdx.x < NREL) h[threadIdx.x] = 0;
    __syncthreads();
    const int b = blockIdx.x;
    const int beg = b * chunk, end = min(E, beg + chunk);
    for (int e = beg + threadIdx.x; e < end; e += 256) {
        atomicAdd(&deg[ei[E + e]], 1.0f);
        atomicAdd(&h[et[e]], 1);
    }
    __syncthreads();
    if (threadIdx.x < NREL) blkcnt[threadIdx.x * NBLK + b] = h[threadIdx.x];
}

// Pass B: one block scans blkcnt[r*NBLK+b] (2048 entries, r-major) -> exclusive bases,
// plus global relation offsets offs[0..8].
__global__ __launch_bounds__(256) void scan_kernel(const int* __restrict__ blkcnt,
                                                   int* __restrict__ ebase,
                                                   int* __restrict__ offs) {
    __shared__ int s[256];
    __shared__ int sofs[NREL];
    const int t = threadIdx.x;
    int v[8]; int loc = 0;
    #pragma unroll
    for (int k = 0; k < 8; ++k) { v[k] = blkcnt[t * 8 + k]; loc += v[k]; }
    s[t] = loc;
    __syncthreads();
    for (int off = 1; off < 256; off <<= 1) {
        int add = (t >= off) ? s[t - off] : 0;
        __syncthreads();
        s[t] += add;
        __syncthreads();
    }
    int base = s[t] - loc;  // exclusive prefix of this thread's 8-entry chunk
    if ((t & 31) == 0) sofs[t >> 5] = base;  // index t*8 == r*NBLK boundary
    int run = base;
    #pragma unroll
    for (int k = 0; k < 8; ++k) { ebase[t * 8 + k] = run; run += v[k]; }
    __syncthreads();
    if (t < NREL) offs[t] = sofs[t];
    if (t == 0) offs[NREL] = s[255];
}

// Pass C: write sorted-by-relation edge records (row<<16|col, coef); LDS cursors only.
__global__ __launch_bounds__(256) void bucket_kernel(const int* __restrict__ ei,
                                                     const int* __restrict__ et,
                                                     const float* __restrict__ ew,
                                                     const float* __restrict__ deg,
                                                     const int* __restrict__ ebase,
                                                     uint2* __restrict__ ebuf,
                                                     int E, int chunk) {
    __shared__ int lofs[NREL];
    const int b = blockIdx.x;
    if (threadIdx.x < NREL) lofs[threadIdx.x] = ebase[threadIdx.x * NBLK + b];
    __syncthreads();
    const int beg = b * chunk, end = min(E, beg + chunk);
    for (int e = beg + threadIdx.x; e < end; e += 256) {
        const int row = ei[e], col = ei[E + e];
        const float coef = dis_f(deg[row]) * dis_f(deg[col]) * ew[e];
        const int pos = atomicAdd(&lofs[et[e]], 1);
        ebuf[pos] = make_uint2(((unsigned)row << 16) | (unsigned)col, __float_as_uint(coef));
    }
}

// Scatter one relation bucket: h[col,:] += coef * src[row,:]
__global__ __launch_bounds__(256) void scatter_kernel(const uint2* __restrict__ ebuf,
                                                      const int* __restrict__ offs, int r,
                                                      const float* __restrict__ src,
                                                      float* __restrict__ hbuf) {
    const int beg = offs[r], end = offs[r + 1];
    const int d = threadIdx.x & (DD - 1);
    const int half = threadIdx.x >> 7;
    const int step = gridDim.x * 2;
    for (int e = beg + blockIdx.x * 2 + half; e < end; e += step) {
        const uint2 rec = ebuf[e];
        const int row = rec.x >> 16, col = rec.x & 0xFFFF;
        const float coef = __uint_as_float(rec.y);
        atomicAdd(&hbuf[(size_t)col * DD + d], coef * src[(size_t)row * DD + d]);
    }
}

// zacc[n,0:128] += h[n,0:128] @ W[128,128]; zeroes consumed h tile behind itself.
__global__ __launch_bounds__(256) void gemm_kernel(float* __restrict__ hbuf,
                                                   const float* __restrict__ W,
                                                   float* __restrict__ zacc, int N) {
    __shared__ float lds[BM * LDH];
    const int t = threadIdx.x;
    const int m0 = blockIdx.x * BM;

    #pragma unroll
    for (int v = t; v < BM * 32; v += 256) {
        const int row = v >> 5, c4 = v & 31;
        const int gr = m0 + row;
        float4 val = make_float4(0.f, 0.f, 0.f, 0.f);
        if (gr < N) {
            float4* gp = (float4*)&hbuf[(size_t)gr * DD + c4 * 4];
            val = *gp;
            *gp = make_float4(0.f, 0.f, 0.f, 0.f);
        }
        *(float4*)&lds[row * LDH + c4 * 4] = val;
    }
    __syncthreads();

    const int i = t >> 4, j = t & 15;
    float acc[4][8];
    #pragma unroll
    for (int m = 0; m < 4; ++m)
        #pragma unroll
        for (int c = 0; c < 8; ++c) acc[m][c] = 0.f;

    const float* lh = &lds[(i * 4) * LDH];
    const float* Wp = W + j * 8;
    #pragma unroll 4
    for (int k = 0; k < DD; ++k) {
        const float4 wa = *(const float4*)&Wp[(size_t)k * DD];
        const float4 wb = *(const float4*)&Wp[(size_t)k * DD + 4];
        float a[4];
        #pragma unroll
        for (int m = 0; m < 4; ++m) a[m] = lh[m * LDH + k];
        #pragma unroll
        for (int m = 0; m < 4; ++m) {
            acc[m][0] += a[m] * wa.x; acc[m][1] += a[m] * wa.y;
            acc[m][2] += a[m] * wa.z; acc[m][3] += a[m] * wa.w;
            acc[m][4] += a[m] * wb.x; acc[m][5] += a[m] * wb.y;
            acc[m][6] += a[m] * wb.z; acc[m][7] += a[m] * wb.w;
        }
    }

    #pragma unroll
    for (int m = 0; m < 4; ++m) {
        const int gr = m0 + i * 4 + m;
        if (gr >= N) continue;
        float4* p = (float4*)&zacc[(size_t)gr * DD + j * 8];
        float4 v0 = p[0], v1 = p[1];
        v0.x += acc[m][0]; v0.y += acc[m][1]; v0.z += acc[m][2]; v0.w += acc[m][3];
        v1.x += acc[m][4]; v1.y += acc[m][5]; v1.z += acc[m][6]; v1.w += acc[m][7];
        p[0] = v0; p[1] = v1;
    }
}

__global__ void act_kernel(float* __restrict__ z, const float* __restrict__ b, int total4) {
    int idx = blockIdx.x * blockDim.x + threadIdx.x;
    if (idx >= total4) return;
    const int c0 = (idx * 4) & (DD - 1);
    float4 v = ((float4*)z)[idx];
    v.x += b[c0 + 0]; v.y += b[c0 + 1]; v.z += b[c0 + 2]; v.w += b[c0 + 3];
    v.x = v.x >= 0.f ? v.x : 0.01f * v.x;
    v.y = v.y >= 0.f ? v.y : 0.01f * v.y;
    v.z = v.z >= 0.f ? v.z : 0.01f * v.z;
    v.w = v.w >= 0.f ? v.w : 0.01f * v.w;
    ((float4*)z)[idx] = v;
}

__global__ void final_kernel(const float* __restrict__ x, const float* __restrict__ b2,
                             float* __restrict__ out, int total4) {
    int idx = blockIdx.x * blockDim.x + threadIdx.x;
    if (idx >= total4) return;
    const int c0 = (idx * 4) & (DD - 1);
    float4 z1 = ((float4*)out)[idx];
    float4 z2 = ((float4*)out)[total4 + idx];
    z2.x += b2[c0 + 0]; z2.y += b2[c0 + 1]; z2.z += b2[c0 + 2]; z2.w += b2[c0 + 3];
    float4 xx = ((const float4*)x)[idx];
    float4 zs, zp;
    zs.x = (xx.x + z1.x + z2.x) * 0.25f; zp.x = (z1.x + z2.x) * (1.f / 3.f);
    zs.y = (xx.y + z1.y + z2.y) * 0.25f; zp.y = (z1.y + z2.y) * (1.f / 3.f);
    zs.z = (xx.z + z1.z + z2.z) * 0.25f; zp.z = (z1.z + z2.z) * (1.f / 3.f);
    zs.w = (xx.w + z1.w + z2.w) * 0.25f; zp.w = (z1.w + z2.w) * (1.f / 3.f);
    ((float4*)out)[idx] = zs;
    ((float4*)out)[total4 + idx] = zp;
}

extern "C" void kernel_launch(void* const* d_in, const int* in_sizes, int n_in,
                              void* d_out, int out_size, void* d_ws, size_t ws_size,
                              hipStream_t stream) {
    const float* x  = (const float*)d_in[0];
    const int*   ei = (const int*)d_in[1];
    const int*   et = (const int*)d_in[2];
    const float* ew = (const float*)d_in[3];
    const float* W1 = (const float*)d_in[4];
    const float* b1 = (const float*)d_in[5];
    const float* W2 = (const float*)d_in[6];
    const float* b2 = (const float*)d_in[7];

    const int N = in_sizes[0] / DD;
    const int E = in_sizes[3];
    const int total = N * DD;
    float* out = (float*)d_out;

    // ws layout: deg[npad] | blkcnt[2048] | ebase[2048] | offs[16] | ebuf[E]*8B | hbuf[N*D]
    char* w = (char*)d_ws;
    const size_t npad = (size_t)((N + 15) / 16) * 16;
    float* deg = (float*)w;            w += npad * 4;
    int* blkcnt = (int*)w;             w += NREL * NBLK * 4;
    int* ebase = (int*)w;              w += NREL * NBLK * 4;
    int* offs = (int*)w;               w += 16 * 4;
    uint2* ebuf = (uint2*)w;           w += (size_t)E * 8;
    float* hbuf = (float*)w;

    // Per-call init: deg accumulates atomically; hbuf is atomic target; out halves RMW-accumulate.
    hipMemsetAsync(deg, 0, npad * 4, stream);
    hipMemsetAsync(hbuf, 0, (size_t)total * 4, stream);
    hipMemsetAsync(d_out, 0, (size_t)total * 2 * 4, stream);

    const int chunk = (E + NBLK - 1) / NBLK;
    count_deg_kernel<<<NBLK, 256, 0, stream>>>(ei, et, deg, blkcnt, E, chunk);
    scan_kernel<<<1, 256, 0, stream>>>(blkcnt, ebase, offs);
    bucket_kernel<<<NBLK, 256, 0, stream>>>(ei, et, ew, deg, ebase, ebuf, E, chunk);

    const int nb = (N + BM - 1) / BM;
    float* z1acc = out;
    float* z2acc = out + total;

    for (int r = 0; r < NREL; ++r) {
        scatter_kernel<<<1024, 256, 0, stream>>>(ebuf, offs, r, x, hbuf);
        gemm_kernel<<<nb, 256, 0, stream>>>(hbuf, W1 + (size_t)r * DD * DD, z1acc, N);
    }
    const int t4 = total / 4;
    act_kernel<<<(t4 + 255) / 256, 256, 0, stream>>>(z1acc, b1, t4);

    for (int r = 0; r < NREL; ++r) {
        scatter_kernel<<<1024, 256, 0, stream>>>(ebuf, offs, r, z1acc, hbuf);
        gemm_kernel<<<nb, 256, 0, stream>>>(hbuf, W2 + (size_t)r * DD * DD, z2acc, N);
    }
    final_kernel<<<(t4 + 255) / 256, 256, 0, stream>>>(x, b2, out, t4);
}

// Round 3
// 506.843 us; speedup vs baseline: 12.1700x; 2.7288x over previous
//
#include <hip/hip_runtime.h>
#include <hip/hip_bf16.h>

#define DD 128
#define NREL 8
#define LDHB 1032   // hb row stride (bf16 elems): 1032*2B=2064B, 516 dwords = 4 mod 32 banks -> 2-way (free)

typedef float f32x4 __attribute__((ext_vector_type(4)));
typedef short short8 __attribute__((ext_vector_type(8)));

__device__ __forceinline__ float dis_f(float deg) {
    return deg == 0.0f ? 1.0f : rsqrtf(deg);
}

// In-degree per target col (50K addresses; ~13-way avg collisions, benign).
__global__ __launch_bounds__(256) void count_kernel(const int* __restrict__ ei,
                                                    int* __restrict__ cnt, int E) {
    int e = blockIdx.x * blockDim.x + threadIdx.x;
    if (e < E) atomicAdd(&cnt[ei[E + e]], 1);
}

// Single-block exclusive scan of cnt[N] -> cur[N] (start offsets; bucket bumps to end offsets).
__global__ __launch_bounds__(1024) void scan_kernel(const int* __restrict__ cnt,
                                                    int* __restrict__ cur, int N) {
    __shared__ int s[1024];
    const int t = threadIdx.x;
    const int chunk = (N + 1023) / 1024;
    const int beg = t * chunk, end = min(N, beg + chunk);
    int sum = 0;
    for (int c = beg; c < end; ++c) sum += cnt[c];
    s[t] = sum;
    __syncthreads();
    for (int off = 1; off < 1024; off <<= 1) {
        int add = (t >= off) ? s[t - off] : 0;
        __syncthreads();
        s[t] += add;
        __syncthreads();
    }
    int run = s[t] - sum;
    for (int c = beg; c < end; ++c) { cur[c] = run; run += cnt[c]; }
}

// Place edge records sorted by col: rec = (et<<16 | row, coef). Requires N<65536, R<=8.
__global__ __launch_bounds__(256) void bucket_kernel(const int* __restrict__ ei,
                                                     const int* __restrict__ et,
                                                     const float* __restrict__ ew,
                                                     const int* __restrict__ cnt,
                                                     int* __restrict__ cur,
                                                     uint2* __restrict__ ebuf, int E) {
    int e = blockIdx.x * blockDim.x + threadIdx.x;
    if (e >= E) return;
    const int row = ei[e], col = ei[E + e];
    const float coef = dis_f((float)cnt[row]) * dis_f((float)cnt[col]) * ew[e];
    const int pos = atomicAdd(&cur[col], 1);
    ebuf[pos] = make_uint2(((unsigned)et[e] << 16) | (unsigned)row, __float_as_uint(coef));
}

// BT[layer][o][r*128+d] = bf16(W[r][d][o]) — transposed so B-fragments are contiguous 16B loads.
__global__ __launch_bounds__(256) void wtrans_kernel(const float* __restrict__ W1,
                                                     const float* __restrict__ W2,
                                                     __hip_bfloat16* __restrict__ BT1,
                                                     __hip_bfloat16* __restrict__ BT2) {
    const int r = blockIdx.x;                       // 0..7
    const float* W = blockIdx.y ? W2 : W1;
    __hip_bfloat16* BT = blockIdx.y ? BT2 : BT1;
    const int d = threadIdx.x & 127;
    const int og0 = threadIdx.x >> 7;               // 0..1
    for (int j = 0; j < 64; ++j) {
        const int o = og0 * 64 + j;
        BT[(size_t)o * 1024 + r * DD + d] =
            __float2bfloat16(W[((size_t)r * DD + d) * DD + o]);
    }
}

// Fused per-layer kernel: CSC register-gather of h[c, r*128+d] -> LDS bf16 -> MFMA with BT.
// Block = 16 cols (MFMA M), 4 waves; wave w gathers cols w*4..w*4+3, then computes
// output slice o in [w*32, w*32+32).
template<int LAYER>
__global__ __launch_bounds__(256) void fused_kernel(const float* __restrict__ src,
                                                    const uint2* __restrict__ ebuf,
                                                    const int* __restrict__ cur,  // END offsets
                                                    const __hip_bfloat16* __restrict__ BT,
                                                    const float* __restrict__ bias,
                                                    const float* __restrict__ x,
                                                    float* __restrict__ z1f,
                                                    float* __restrict__ out, int N) {
    __shared__ __hip_bfloat16 hb[16][LDHB];
    const int tid = threadIdx.x;
    const int w = tid >> 6, l = tid & 63;
    const int c0 = blockIdx.x * 16;

    // ---- gather phase: h accumulated in registers, compile-time indexed via uniform switch
    for (int q = 0; q < 4; ++q) {
        const int m = w * 4 + q;
        const int c = c0 + m;
        float acc[16];
        #pragma unroll
        for (int i = 0; i < 16; ++i) acc[i] = 0.f;
        if (c < N) {
            const int beg = (c > 0) ? cur[c - 1] : 0;
            const int end = cur[c];
            int e = beg;
            uint2 r0 = make_uint2(0u, 0u), r1 = make_uint2(0u, 0u);
            float2 xv = make_float2(0.f, 0.f);
            if (e < end) {
                r0 = ebuf[e];
                xv = *(const float2*)&src[(size_t)(r0.x & 0xffffu) * DD + 2 * l];
            }
            if (e + 1 < end) r1 = ebuf[e + 1];
            for (; e < end; ++e) {
                const unsigned meta = r0.x;
                const float cf = __uint_as_float(r0.y);
                const float2 xc = xv;
                r0 = r1;                                  // rotate prefetch
                if (e + 2 < end) r1 = ebuf[e + 2];
                if (e + 1 < end)
                    xv = *(const float2*)&src[(size_t)(r0.x & 0xffffu) * DD + 2 * l];
                switch (meta >> 16) {                     // wave-uniform branch
                    case 0: acc[0] += cf*xc.x;  acc[1] += cf*xc.y;  break;
                    case 1: acc[2] += cf*xc.x;  acc[3] += cf*xc.y;  break;
                    case 2: acc[4] += cf*xc.x;  acc[5] += cf*xc.y;  break;
                    case 3: acc[6] += cf*xc.x;  acc[7] += cf*xc.y;  break;
                    case 4: acc[8] += cf*xc.x;  acc[9] += cf*xc.y;  break;
                    case 5: acc[10] += cf*xc.x; acc[11] += cf*xc.y; break;
                    case 6: acc[12] += cf*xc.x; acc[13] += cf*xc.y; break;
                    default: acc[14] += cf*xc.x; acc[15] += cf*xc.y; break;
                }
            }
        }
        #pragma unroll
        for (int r = 0; r < NREL; ++r) {
            __hip_bfloat162 p = __float22bfloat162_rn(make_float2(acc[2 * r], acc[2 * r + 1]));
            *(unsigned int*)&hb[m][r * DD + 2 * l] = *(unsigned int*)&p;
        }
    }
    __syncthreads();

    // ---- MFMA phase: z[c0..c0+15][o] = h @ BT^T, K=1024
    const int lk = (l >> 4) * 8;
    const int lr = l & 15;
    f32x4 acc0 = {0.f, 0.f, 0.f, 0.f}, acc1 = {0.f, 0.f, 0.f, 0.f};
    const __hip_bfloat16* bt0 = BT + (size_t)(w * 32 + lr) * 1024 + lk;
    const __hip_bfloat16* bt1 = bt0 + (size_t)16 * 1024;
    const __hip_bfloat16* ha = &hb[lr][lk];
    #pragma unroll 8
    for (int k0 = 0; k0 < 1024; k0 += 32) {
        const short8 a  = *(const short8*)(ha + k0);
        const short8 b0 = *(const short8*)(bt0 + k0);
        const short8 b1 = *(const short8*)(bt1 + k0);
        acc0 = __builtin_amdgcn_mfma_f32_16x16x32_bf16(a, b0, acc0, 0, 0, 0);
        acc1 = __builtin_amdgcn_mfma_f32_16x16x32_bf16(a, b1, acc1, 0, 0, 0);
    }

    // ---- epilogue: D row=(l>>4)*4+q, col=l&15
    const int rbase = (l >> 4) * 4;
    #pragma unroll
    for (int f = 0; f < 2; ++f) {
        const f32x4 av = f ? acc1 : acc0;
        const int o = w * 32 + f * 16 + lr;
        const float bv = bias[o];
        #pragma unroll
        for (int q = 0; q < 4; ++q) {
            const int c = c0 + rbase + q;
            if (c >= N) continue;
            const size_t idx = (size_t)c * DD + o;
            float v = av[q] + bv;
            if (LAYER == 1) {
                v = v >= 0.f ? v : 0.01f * v;   // leaky_relu
                z1f[idx] = v;
            } else {
                const float z1v = z1f[idx];
                const float xv2 = x[idx];
                out[idx] = (xv2 + z1v + v) * 0.25f;                  // z_star
                out[(size_t)N * DD + idx] = (z1v + v) * (1.f / 3.f); // z_sharp
            }
        }
    }
}

extern "C" void kernel_launch(void* const* d_in, const int* in_sizes, int n_in,
                              void* d_out, int out_size, void* d_ws, size_t ws_size,
                              hipStream_t stream) {
    const float* x  = (const float*)d_in[0];
    const int*   ei = (const int*)d_in[1];
    const int*   et = (const int*)d_in[2];
    const float* ew = (const float*)d_in[3];
    const float* W1 = (const float*)d_in[4];
    const float* b1 = (const float*)d_in[5];
    const float* W2 = (const float*)d_in[6];
    const float* b2 = (const float*)d_in[7];

    const int N = in_sizes[0] / DD;
    const int E = in_sizes[3];
    float* out = (float*)d_out;

    // ws layout: cnt[N] | cur[N] | BT1 | BT2 | ebuf[E]*8B | z1f[N*D] fp32  (~31.6 MB)
    char* w = (char*)d_ws;
    int* cnt = (int*)w;                 w += (size_t)N * 4;
    int* cur = (int*)w;                 w += (size_t)N * 4;
    __hip_bfloat16* BT1 = (__hip_bfloat16*)w;  w += (size_t)DD * NREL * DD * 2;
    __hip_bfloat16* BT2 = (__hip_bfloat16*)w;  w += (size_t)DD * NREL * DD * 2;
    uint2* ebuf = (uint2*)w;            w += (size_t)E * 8;
    float* z1f = (float*)w;

    hipMemsetAsync(cnt, 0, (size_t)N * 4, stream);

    const int eb = (E + 255) / 256;
    count_kernel<<<eb, 256, 0, stream>>>(ei, cnt, E);
    wtrans_kernel<<<dim3(NREL, 2), 256, 0, stream>>>(W1, W2, BT1, BT2);
    scan_kernel<<<1, 1024, 0, stream>>>(cnt, cur, N);
    bucket_kernel<<<eb, 256, 0, stream>>>(ei, et, ew, cnt, cur, ebuf, E);

    const int nb = (N + 15) / 16;
    fused_kernel<1><<<nb, 256, 0, stream>>>(x,   ebuf, cur, BT1, b1, x, z1f, out, N);
    fused_kernel<2><<<nb, 256, 0, stream>>>(z1f, ebuf, cur, BT2, b2, x, z1f, out, N);
}

// Round 4
// 422.384 us; speedup vs baseline: 14.6035x; 1.2000x over previous
//
#include <hip/hip_runtime.h>
#include <hip/hip_bf16.h>

#define DD 128
#define NREL 8
#define LDHB 1032   // hb row stride (bf16): 2064B = 516 dwords = 4 mod 32 banks -> 2-way (free, m136)

typedef float f32x4 __attribute__((ext_vector_type(4)));
typedef short short8 __attribute__((ext_vector_type(8)));

__device__ __forceinline__ float dis_f(float deg) {
    return deg == 0.0f ? 1.0f : rsqrtf(deg);
}

// In-degree per target col (50K addresses; ~13-way avg collisions, benign).
__global__ __launch_bounds__(256) void count_kernel(const int* __restrict__ ei,
                                                    int* __restrict__ cnt, int E) {
    int e = blockIdx.x * blockDim.x + threadIdx.x;
    if (e < E) atomicAdd(&cnt[ei[E + e]], 1);
}

// Single-block exclusive scan of cnt[N] -> cur[N] (start offsets; bucket bumps to end offsets).
__global__ __launch_bounds__(1024) void scan_kernel(const int* __restrict__ cnt,
                                                    int* __restrict__ cur, int N) {
    __shared__ int s[1024];
    const int t = threadIdx.x;
    const int chunk = (N + 1023) / 1024;
    const int beg = t * chunk, end = min(N, beg + chunk);
    int sum = 0;
    for (int c = beg; c < end; ++c) sum += cnt[c];
    s[t] = sum;
    __syncthreads();
    for (int off = 1; off < 1024; off <<= 1) {
        int add = (t >= off) ? s[t - off] : 0;
        __syncthreads();
        s[t] += add;
        __syncthreads();
    }
    int run = s[t] - sum;
    for (int c = beg; c < end; ++c) { cur[c] = run; run += cnt[c]; }
}

// Place edge records sorted by col: rec = (et<<16 | row, coef). Requires N<65536, R<=8.
__global__ __launch_bounds__(256) void bucket_kernel(const int* __restrict__ ei,
                                                     const int* __restrict__ et,
                                                     const float* __restrict__ ew,
                                                     const int* __restrict__ cnt,
                                                     int* __restrict__ cur,
                                                     uint2* __restrict__ ebuf, int E) {
    int e = blockIdx.x * blockDim.x + threadIdx.x;
    if (e >= E) return;
    const int row = ei[e], col = ei[E + e];
    const float coef = dis_f((float)cnt[row]) * dis_f((float)cnt[col]) * ew[e];
    const int pos = atomicAdd(&cur[col], 1);
    ebuf[pos] = make_uint2(((unsigned)et[e] << 16) | (unsigned)row, __float_as_uint(coef));
}

// BT[layer][o][r*128+d] = bf16(W[r][d][o]).
__global__ __launch_bounds__(256) void wtrans_kernel(const float* __restrict__ W1,
                                                     const float* __restrict__ W2,
                                                     __hip_bfloat16* __restrict__ BT1,
                                                     __hip_bfloat16* __restrict__ BT2) {
    const int r = blockIdx.x;
    const float* W = blockIdx.y ? W2 : W1;
    __hip_bfloat16* BT = blockIdx.y ? BT2 : BT1;
    const int d = threadIdx.x & 127;
    const int og0 = threadIdx.x >> 7;
    for (int j = 0; j < 64; ++j) {
        const int o = og0 * 64 + j;
        BT[(size_t)o * 1024 + r * DD + d] =
            __float2bfloat16(W[((size_t)r * DD + d) * DD + o]);
    }
}

// x (fp32) -> xb (bf16), 4 elems/thread.
__global__ __launch_bounds__(256) void xcvt_kernel(const float* __restrict__ x,
                                                   __hip_bfloat16* __restrict__ xb, int total4) {
    int i = blockIdx.x * blockDim.x + threadIdx.x;
    if (i >= total4) return;
    const float4 a = ((const float4*)x)[i];
    __hip_bfloat162 p0 = __float22bfloat162_rn(make_float2(a.x, a.y));
    __hip_bfloat162 p1 = __float22bfloat162_rn(make_float2(a.z, a.w));
    uint2 u;
    u.x = *(unsigned int*)&p0;
    u.y = *(unsigned int*)&p1;
    *(uint2*)&xb[(size_t)i * 4] = u;
}

// acc[2r] += coef*elem(2l), acc[2r+1] += coef*elem(2l+1); bf16 pair unpacked via bit ops.
#define ACCUM(RQ, VV) do {                                              \
    const float cf_ = __uint_as_float((RQ).y);                          \
    const float xl_ = __uint_as_float((VV) << 16);                      \
    const float xh_ = __uint_as_float((VV) & 0xffff0000u);              \
    switch ((RQ).x >> 16) {                                             \
        case 0: acc[0]  += cf_*xl_; acc[1]  += cf_*xh_; break;          \
        case 1: acc[2]  += cf_*xl_; acc[3]  += cf_*xh_; break;          \
        case 2: acc[4]  += cf_*xl_; acc[5]  += cf_*xh_; break;          \
        case 3: acc[6]  += cf_*xl_; acc[7]  += cf_*xh_; break;          \
        case 4: acc[8]  += cf_*xl_; acc[9]  += cf_*xh_; break;          \
        case 5: acc[10] += cf_*xl_; acc[11] += cf_*xh_; break;          \
        case 6: acc[12] += cf_*xl_; acc[13] += cf_*xh_; break;          \
        default: acc[14] += cf_*xl_; acc[15] += cf_*xh_; break;         \
    } } while (0)

// Fused per-layer kernel: CSC register-gather (bf16 src, 4-deep pipelined) -> LDS -> MFMA.
template<int LAYER>
__global__ __launch_bounds__(256) void fused_kernel(const __hip_bfloat16* __restrict__ srcb,
                                                    const uint2* __restrict__ ebuf,
                                                    const int* __restrict__ cur,  // END offsets
                                                    const __hip_bfloat16* __restrict__ BT,
                                                    const float* __restrict__ bias,
                                                    const float* __restrict__ x,
                                                    __hip_bfloat16* __restrict__ z1b,
                                                    float* __restrict__ out, int N) {
    __shared__ __hip_bfloat16 hb[16][LDHB];
    const int tid = threadIdx.x;
    const int w = tid >> 6, l = tid & 63;
    const int c0 = blockIdx.x * 16;

    // ---- gather: 4 cols per wave, edges 4-wide with next-group record prefetch
    for (int q = 0; q < 4; ++q) {
        const int m = w * 4 + q;
        const int c = c0 + m;
        float acc[16];
        #pragma unroll
        for (int i = 0; i < 16; ++i) acc[i] = 0.f;
        if (c < N) {
            int beg = (c > 0) ? cur[c - 1] : 0;
            int end = cur[c];
            beg = __builtin_amdgcn_readfirstlane(beg);
            end = __builtin_amdgcn_readfirstlane(end);
            int e = beg;
            uint2 qa0 = make_uint2(0u, 0u), qa1 = qa0, qa2 = qa0, qa3 = qa0;
            if (e + 4 <= end) {
                qa0 = ebuf[e]; qa1 = ebuf[e + 1]; qa2 = ebuf[e + 2]; qa3 = ebuf[e + 3];
            }
            while (e + 4 <= end) {
                const unsigned v0 = *(const unsigned*)&srcb[(size_t)(qa0.x & 0xffffu) * DD + 2 * l];
                const unsigned v1 = *(const unsigned*)&srcb[(size_t)(qa1.x & 0xffffu) * DD + 2 * l];
                const unsigned v2 = *(const unsigned*)&srcb[(size_t)(qa2.x & 0xffffu) * DD + 2 * l];
                const unsigned v3 = *(const unsigned*)&srcb[(size_t)(qa3.x & 0xffffu) * DD + 2 * l];
                uint2 qb0, qb1, qb2, qb3;
                const bool more = (e + 8 <= end);
                if (more) {
                    qb0 = ebuf[e + 4]; qb1 = ebuf[e + 5]; qb2 = ebuf[e + 6]; qb3 = ebuf[e + 7];
                }
                ACCUM(qa0, v0); ACCUM(qa1, v1); ACCUM(qa2, v2); ACCUM(qa3, v3);
                if (more) { qa0 = qb0; qa1 = qb1; qa2 = qb2; qa3 = qb3; }
                e += 4;
            }
            for (; e < end; ++e) {
                const uint2 qq = ebuf[e];
                const unsigned vv = *(const unsigned*)&srcb[(size_t)(qq.x & 0xffffu) * DD + 2 * l];
                ACCUM(qq, vv);
            }
        }
        #pragma unroll
        for (int r = 0; r < NREL; ++r) {
            __hip_bfloat162 p = __float22bfloat162_rn(make_float2(acc[2 * r], acc[2 * r + 1]));
            *(unsigned int*)&hb[m][r * DD + 2 * l] = *(unsigned int*)&p;
        }
    }
    __syncthreads();

    // ---- MFMA phase: z[c0..c0+15][o] = h @ BT^T, K=1024
    const int lk = (l >> 4) * 8;
    const int lr = l & 15;
    f32x4 acc0 = {0.f, 0.f, 0.f, 0.f}, acc1 = {0.f, 0.f, 0.f, 0.f};
    const __hip_bfloat16* bt0 = BT + (size_t)(w * 32 + lr) * 1024 + lk;
    const __hip_bfloat16* bt1 = bt0 + (size_t)16 * 1024;
    const __hip_bfloat16* ha = &hb[lr][lk];
    #pragma unroll 8
    for (int k0 = 0; k0 < 1024; k0 += 32) {
        const short8 a  = *(const short8*)(ha + k0);
        const short8 b0 = *(const short8*)(bt0 + k0);
        const short8 b1 = *(const short8*)(bt1 + k0);
        acc0 = __builtin_amdgcn_mfma_f32_16x16x32_bf16(a, b0, acc0, 0, 0, 0);
        acc1 = __builtin_amdgcn_mfma_f32_16x16x32_bf16(a, b1, acc1, 0, 0, 0);
    }

    // ---- epilogue: D row=(l>>4)*4+q, col=l&15
    const int rbase = (l >> 4) * 4;
    #pragma unroll
    for (int f = 0; f < 2; ++f) {
        const f32x4 av = f ? acc1 : acc0;
        const int o = w * 32 + f * 16 + lr;
        const float bv = bias[o];
        #pragma unroll
        for (int q = 0; q < 4; ++q) {
            const int c = c0 + rbase + q;
            if (c >= N) continue;
            const size_t idx = (size_t)c * DD + o;
            float v = av[q] + bv;
            if (LAYER == 1) {
                v = v >= 0.f ? v : 0.01f * v;   // leaky_relu
                z1b[idx] = __float2bfloat16(v);
            } else {
                const float z1v = __bfloat162float(z1b[idx]);
                const float xv2 = x[idx];
                out[idx] = (xv2 + z1v + v) * 0.25f;                  // z_star
                out[(size_t)N * DD + idx] = (z1v + v) * (1.f / 3.f); // z_sharp
            }
        }
    }
}

extern "C" void kernel_launch(void* const* d_in, const int* in_sizes, int n_in,
                              void* d_out, int out_size, void* d_ws, size_t ws_size,
                              hipStream_t stream) {
    const float* x  = (const float*)d_in[0];
    const int*   ei = (const int*)d_in[1];
    const int*   et = (const int*)d_in[2];
    const float* ew = (const float*)d_in[3];
    const float* W1 = (const float*)d_in[4];
    const float* b1 = (const float*)d_in[5];
    const float* W2 = (const float*)d_in[6];
    const float* b2 = (const float*)d_in[7];

    const int N = in_sizes[0] / DD;
    const int E = in_sizes[3];
    float* out = (float*)d_out;

    // ws: cnt[N] | cur[N] | BT1 | BT2 | ebuf[E]*8B | xb[N*D]bf16 | z1b[N*D]bf16  (~30.2 MiB)
    char* w = (char*)d_ws;
    int* cnt = (int*)w;                 w += (size_t)N * 4;
    int* cur = (int*)w;                 w += (size_t)N * 4;
    __hip_bfloat16* BT1 = (__hip_bfloat16*)w;  w += (size_t)DD * NREL * DD * 2;
    __hip_bfloat16* BT2 = (__hip_bfloat16*)w;  w += (size_t)DD * NREL * DD * 2;
    uint2* ebuf = (uint2*)w;            w += (size_t)E * 8;
    __hip_bfloat16* xb = (__hip_bfloat16*)w;   w += (size_t)N * DD * 2;
    __hip_bfloat16* z1b = (__hip_bfloat16*)w;

    hipMemsetAsync(cnt, 0, (size_t)N * 4, stream);

    const int eb = (E + 255) / 256;
    count_kernel<<<eb, 256, 0, stream>>>(ei, cnt, E);
    wtrans_kernel<<<dim3(NREL, 2), 256, 0, stream>>>(W1, W2, BT1, BT2);
    const int t4 = N * DD / 4;
    xcvt_kernel<<<(t4 + 255) / 256, 256, 0, stream>>>(x, xb, t4);
    scan_kernel<<<1, 1024, 0, stream>>>(cnt, cur, N);
    bucket_kernel<<<eb, 256, 0, stream>>>(ei, et, ew, cnt, cur, ebuf, E);

    const int nb = (N + 15) / 16;
    fused_kernel<1><<<nb, 256, 0, stream>>>(xb,  ebuf, cur, BT1, b1, x, z1b, out, N);
    fused_kernel<2><<<nb, 256, 0, stream>>>(z1b, ebuf, cur, BT2, b2, x, z1b, out, N);
}

// Round 5
// 407.839 us; speedup vs baseline: 15.1243x; 1.0357x over previous
//
#include <hip/hip_runtime.h>
#include <hip/hip_bf16.h>

#define DD 128
#define NREL 8
#define LDHB 1032   // hb row stride (bf16): 2064B = 516 dwords = 4 mod 32 banks -> 2-way (free, m136)
#define BC 32       // cols per block
#define RECCAP 1024 // LDS record buffer entries (block mean ~410; Poisson tail >1024 impossible)

typedef float f32x4 __attribute__((ext_vector_type(4)));
typedef short short8 __attribute__((ext_vector_type(8)));

__device__ __forceinline__ float dis_f(float deg) {
    return deg == 0.0f ? 1.0f : rsqrtf(deg);
}

// In-degree per target col (50K addresses; ~13-way avg collisions, benign).
__global__ __launch_bounds__(256) void count_kernel(const int* __restrict__ ei,
                                                    int* __restrict__ cnt, int E) {
    int e = blockIdx.x * blockDim.x + threadIdx.x;
    if (e < E) atomicAdd(&cnt[ei[E + e]], 1);
}

// Single-block exclusive scan of cnt[N] -> cur[N] (start offsets; bucket bumps to end offsets).
__global__ __launch_bounds__(1024) void scan_kernel(const int* __restrict__ cnt,
                                                    int* __restrict__ cur, int N) {
    __shared__ int s[1024];
    const int t = threadIdx.x;
    const int chunk = (((N + 1023) / 1024) + 3) & ~3;
    const int beg = t * chunk, end = min(N, beg + chunk);
    int sum = 0;
    int c = beg;
    for (; c + 4 <= end; c += 4) {
        const int4 v = *(const int4*)&cnt[c];
        sum += v.x + v.y + v.z + v.w;
    }
    for (; c < end; ++c) sum += cnt[c];
    s[t] = sum;
    __syncthreads();
    for (int off = 1; off < 1024; off <<= 1) {
        int add = (t >= off) ? s[t - off] : 0;
        __syncthreads();
        s[t] += add;
        __syncthreads();
    }
    int run = s[t] - sum;
    for (int cc = beg; cc < end; ++cc) { cur[cc] = run; run += cnt[cc]; }
}

// Place edge records sorted by col: rec = (et<<16 | row, coef). Requires N<65536, R<=8.
__global__ __launch_bounds__(256) void bucket_kernel(const int* __restrict__ ei,
                                                     const int* __restrict__ et,
                                                     const float* __restrict__ ew,
                                                     const int* __restrict__ cnt,
                                                     int* __restrict__ cur,
                                                     uint2* __restrict__ ebuf, int E) {
    int e = blockIdx.x * blockDim.x + threadIdx.x;
    if (e >= E) return;
    const int row = ei[e], col = ei[E + e];
    const float coef = dis_f((float)cnt[row]) * dis_f((float)cnt[col]) * ew[e];
    const int pos = atomicAdd(&cur[col], 1);
    ebuf[pos] = make_uint2(((unsigned)et[e] << 16) | (unsigned)row, __float_as_uint(coef));
}

// BT[o][r*128+d] = bf16(W[r][d][o]) via LDS tile transpose (coalesced both sides).
__global__ __launch_bounds__(256) void wtrans_kernel(const float* __restrict__ W1,
                                                     const float* __restrict__ W2,
                                                     __hip_bfloat16* __restrict__ BT1,
                                                     __hip_bfloat16* __restrict__ BT2) {
    __shared__ __hip_bfloat16 tile[128][130];
    const int r = blockIdx.x & 7;
    const float* W = (blockIdx.x >> 3) ? W2 : W1;
    __hip_bfloat16* BT = (blockIdx.x >> 3) ? BT2 : BT1;
    const int o = threadIdx.x & 127;
    const int h = threadIdx.x >> 7;
    for (int d = h; d < DD; d += 2)
        tile[d][o] = __float2bfloat16(W[((size_t)r * DD + d) * DD + o]);
    __syncthreads();
    const int d = threadIdx.x & 127;
    for (int o2 = h; o2 < DD; o2 += 2)
        BT[(size_t)o2 * 1024 + r * DD + d] = tile[d][o2];
}

// x (fp32) -> xb (bf16), 4 elems/thread.
__global__ __launch_bounds__(256) void xcvt_kernel(const float* __restrict__ x,
                                                   __hip_bfloat16* __restrict__ xb, int total4) {
    int i = blockIdx.x * blockDim.x + threadIdx.x;
    if (i >= total4) return;
    const float4 a = ((const float4*)x)[i];
    __hip_bfloat162 p0 = __float22bfloat162_rn(make_float2(a.x, a.y));
    __hip_bfloat162 p1 = __float22bfloat162_rn(make_float2(a.z, a.w));
    uint2 u;
    u.x = *(unsigned int*)&p0;
    u.y = *(unsigned int*)&p1;
    *(uint2*)&xb[(size_t)i * 4] = u;
}

// acc[Q][2r] += coef*lo(v), acc[Q][2r+1] += coef*hi(v); meta/coef are wave-uniform (scalar).
#define ACCUM(Q, MS, CF, VV) do {                                          \
    const float xl_ = __uint_as_float((VV) << 16);                         \
    const float xh_ = __uint_as_float((VV) & 0xffff0000u);                 \
    switch ((MS) >> 16) {                                                  \
        case 0: acc[Q][0]  += (CF)*xl_; acc[Q][1]  += (CF)*xh_; break;     \
        case 1: acc[Q][2]  += (CF)*xl_; acc[Q][3]  += (CF)*xh_; break;     \
        case 2: acc[Q][4]  += (CF)*xl_; acc[Q][5]  += (CF)*xh_; break;     \
        case 3: acc[Q][6]  += (CF)*xl_; acc[Q][7]  += (CF)*xh_; break;     \
        case 4: acc[Q][8]  += (CF)*xl_; acc[Q][9]  += (CF)*xh_; break;     \
        case 5: acc[Q][10] += (CF)*xl_; acc[Q][11] += (CF)*xh_; break;     \
        case 6: acc[Q][12] += (CF)*xl_; acc[Q][13] += (CF)*xh_; break;     \
        default: acc[Q][14] += (CF)*xl_; acc[Q][15] += (CF)*xh_; break;    \
    } } while (0)

// Fused per-layer: records staged to LDS (coalesced) -> scalar-addressed 8-deep
// register gather -> LDS h tile -> MFMA with BT. Block = 32 cols, 8 waves.
// Wave w gathers cols w*4..w*4+3; MFMA: wave w computes o-slice [w*16,w*16+16) x 32 rows.
template<int LAYER>
__global__ __launch_bounds__(512, 4) void fused_kernel(const __hip_bfloat16* __restrict__ srcb,
                                                       const uint2* __restrict__ ebuf,
                                                       const int* __restrict__ cur,  // END offsets
                                                       const __hip_bfloat16* __restrict__ BT,
                                                       const float* __restrict__ bias,
                                                       const float* __restrict__ x,
                                                       __hip_bfloat16* __restrict__ z1b,
                                                       float* __restrict__ out, int N) {
    __shared__ __hip_bfloat16 hb[BC][LDHB];
    __shared__ uint2 recs[RECCAP];
    const int tid = threadIdx.x;
    const int w = tid >> 6, l = tid & 63;
    const int c0 = blockIdx.x * BC;

    float acc[4][16];
    #pragma unroll
    for (int q = 0; q < 4; ++q)
        #pragma unroll
        for (int i = 0; i < 16; ++i) acc[q][i] = 0.f;

    const int B0 = (c0 > 0) ? cur[c0 - 1] : 0;
    const int B1 = cur[min(c0 + BC - 1, N - 1)];

    for (int cb = B0; cb < B1; cb += RECCAP) {
        const int ce = min(B1, cb + RECCAP);
        for (int i = cb + tid; i < ce; i += 512) recs[i - cb] = ebuf[i];
        __syncthreads();
        #pragma unroll
        for (int q = 0; q < 4; ++q) {
            const int c = c0 + w * 4 + q;
            if (c < N) {
                const int bc = (c > 0) ? cur[c - 1] : 0;
                const int ec = cur[c];
                const int lo = max(bc, cb), hi = min(ec, ce);
                int e = lo;
                while (e + 8 <= hi) {
                    unsigned ms[8]; float cf[8]; unsigned v[8];
                    #pragma unroll
                    for (int i = 0; i < 8; ++i) {
                        const uint2 rr = recs[e - cb + i];
                        ms[i] = (unsigned)__builtin_amdgcn_readfirstlane((int)rr.x);
                        cf[i] = __uint_as_float((unsigned)__builtin_amdgcn_readfirstlane((int)rr.y));
                    }
                    #pragma unroll
                    for (int i = 0; i < 8; ++i)
                        v[i] = *(const unsigned*)&srcb[(size_t)(ms[i] & 0xffffu) * DD + 2 * l];
                    #pragma unroll
                    for (int i = 0; i < 8; ++i) ACCUM(q, ms[i], cf[i], v[i]);
                    e += 8;
                }
                for (; e < hi; ++e) {
                    const uint2 rr = recs[e - cb];
                    const unsigned m1 = (unsigned)__builtin_amdgcn_readfirstlane((int)rr.x);
                    const float c1 = __uint_as_float((unsigned)__builtin_amdgcn_readfirstlane((int)rr.y));
                    const unsigned v1 = *(const unsigned*)&srcb[(size_t)(m1 & 0xffffu) * DD + 2 * l];
                    ACCUM(q, m1, c1, v1);
                }
            }
        }
        __syncthreads();
    }

    // h -> LDS (bf16)
    #pragma unroll
    for (int q = 0; q < 4; ++q) {
        const int m = w * 4 + q;
        #pragma unroll
        for (int r = 0; r < NREL; ++r) {
            __hip_bfloat162 p = __float22bfloat162_rn(make_float2(acc[q][2 * r], acc[q][2 * r + 1]));
            *(unsigned int*)&hb[m][r * DD + 2 * l] = *(unsigned int*)&p;
        }
    }
    __syncthreads();

    // ---- MFMA: 2 row-tiles (rows 0-15, 16-31) x shared B-slice o=[w*16,w*16+16), K=1024
    const int lk = (l >> 4) * 8;
    const int lr = l & 15;
    f32x4 acc0 = {0.f, 0.f, 0.f, 0.f}, acc1 = {0.f, 0.f, 0.f, 0.f};
    const __hip_bfloat16* bt = BT + (size_t)(w * 16 + lr) * 1024 + lk;
    const __hip_bfloat16* h0 = &hb[lr][lk];
    const __hip_bfloat16* h1 = &hb[16 + lr][lk];
    #pragma unroll 8
    for (int k0 = 0; k0 < 1024; k0 += 32) {
        const short8 b  = *(const short8*)(bt + k0);
        const short8 a0 = *(const short8*)(h0 + k0);
        const short8 a1 = *(const short8*)(h1 + k0);
        acc0 = __builtin_amdgcn_mfma_f32_16x16x32_bf16(a0, b, acc0, 0, 0, 0);
        acc1 = __builtin_amdgcn_mfma_f32_16x16x32_bf16(a1, b, acc1, 0, 0, 0);
    }

    // ---- epilogue: D row=(l>>4)*4+q (graph col), col=l&15 (o)
    const int rbase = (l >> 4) * 4;
    const int o = w * 16 + lr;
    const float bv = bias[o];
    #pragma unroll
    for (int t = 0; t < 2; ++t) {
        const f32x4 av = t ? acc1 : acc0;
        #pragma unroll
        for (int q = 0; q < 4; ++q) {
            const int c = c0 + t * 16 + rbase + q;
            if (c >= N) continue;
            const size_t idx = (size_t)c * DD + o;
            float v = av[q] + bv;
            if (LAYER == 1) {
                v = v >= 0.f ? v : 0.01f * v;   // leaky_relu
                z1b[idx] = __float2bfloat16(v);
            } else {
                const float z1v = __bfloat162float(z1b[idx]);
                const float xv2 = x[idx];
                out[idx] = (xv2 + z1v + v) * 0.25f;                  // z_star
                out[(size_t)N * DD + idx] = (z1v + v) * (1.f / 3.f); // z_sharp
            }
        }
    }
}

extern "C" void kernel_launch(void* const* d_in, const int* in_sizes, int n_in,
                              void* d_out, int out_size, void* d_ws, size_t ws_size,
                              hipStream_t stream) {
    const float* x  = (const float*)d_in[0];
    const int*   ei = (const int*)d_in[1];
    const int*   et = (const int*)d_in[2];
    const float* ew = (const float*)d_in[3];
    const float* W1 = (const float*)d_in[4];
    const float* b1 = (const float*)d_in[5];
    const float* W2 = (const float*)d_in[6];
    const float* b2 = (const float*)d_in[7];

    const int N = in_sizes[0] / DD;
    const int E = in_sizes[3];
    float* out = (float*)d_out;

    // ws: cnt[N] | cur[N] | BT1 | BT2 | ebuf[E]*8B | xb[N*D]bf16 | z1b[N*D]bf16  (~31.6 MiB)
    char* w = (char*)d_ws;
    int* cnt = (int*)w;                 w += (size_t)N * 4;
    int* cur = (int*)w;                 w += (size_t)N * 4;
    __hip_bfloat16* BT1 = (__hip_bfloat16*)w;  w += (size_t)DD * NREL * DD * 2;
    __hip_bfloat16* BT2 = (__hip_bfloat16*)w;  w += (size_t)DD * NREL * DD * 2;
    uint2* ebuf = (uint2*)w;            w += (size_t)E * 8;
    __hip_bfloat16* xb = (__hip_bfloat16*)w;   w += (size_t)N * DD * 2;
    __hip_bfloat16* z1b = (__hip_bfloat16*)w;

    hipMemsetAsync(cnt, 0, (size_t)N * 4, stream);

    const int eb = (E + 255) / 256;
    count_kernel<<<eb, 256, 0, stream>>>(ei, cnt, E);
    wtrans_kernel<<<16, 256, 0, stream>>>(W1, W2, BT1, BT2);
    const int t4 = N * DD / 4;
    xcvt_kernel<<<(t4 + 255) / 256, 256, 0, stream>>>(x, xb, t4);
    scan_kernel<<<1, 1024, 0, stream>>>(cnt, cur, N);
    bucket_kernel<<<eb, 256, 0, stream>>>(ei, et, ew, cnt, cur, ebuf, E);

    const int nb = (N + BC - 1) / BC;
    fused_kernel<1><<<nb, 512, 0, stream>>>(xb,  ebuf, cur, BT1, b1, x, z1b, out, N);
    fused_kernel<2><<<nb, 512, 0, stream>>>(z1b, ebuf, cur, BT2, b2, x, z1b, out, N);
}